// Round 13
// baseline (432.203 us; speedup 1.0000x reference)
//
#include <hip/hip_runtime.h>
#include <hip/hip_bf16.h>
#include <math.h>

// ---------------------------------------------------------------------------
// EvolveGCNH + GCNConv + EdgeDecoder.
// R1..R14: CSR bucket sort, quad gather/decode, MFMA GEMMs, meta preload
//          (467 us). R15: persistent waves regressed — decode/gather at the
//          gather-path wall (~68us each). R18: 455. R19: co-launched chains
//          -> 405.6 (BEST; boundary ~12us/launch).
// R20-R23: algebraic reorder (GEMM1 deleted) never beat R19 (best 419.5).
//      Ledger says the "redundant" GEMM1 acts as an L2 PREFETCH: it writes
//      xwh (25.6MB < 32MB L2) immediately before gather's random reads;
//      deleting it made the gather stream L2-cold (+20-30us). R23's
//      coalesced p1 write-out was NEUTRAL (scatter-write theory falsified).
// R24 (this round): revert to the R19 structure exactly (GEMM1 + warm
//      gather), keeping only the independently-sound deltas from R20-22:
//      - lin1cast folded into fusedA; private-row histograms (plain stores,
//        no zero pass) -> init launch deleted (9 -> 8 launches).
//      - fusedB scan parallelized (2-way row sums).
//      - fusedC topk sums 64 private ghp rows (hidden under p1).
// ---------------------------------------------------------------------------

typedef __attribute__((ext_vector_type(8))) short bf16x8;
typedef __attribute__((ext_vector_type(8))) unsigned short u16x8;
typedef __attribute__((ext_vector_type(4))) float f32x4;

#define WSHIFT 9              // 512 nodes per bucket
#define WMASK 511
#define NBUCK 98              // ceil(50000/512)

__device__ __forceinline__ unsigned f2key(float f) {
  unsigned u = __float_as_uint(f);
  return (u & 0x80000000u) ? ~u : (u | 0x80000000u);
}

// round-to-nearest-even fp32 -> bf16 bits
__device__ __forceinline__ unsigned short f2bf(float f) {
  unsigned u = __float_as_uint(f);
  unsigned r = u + 0x7fffu + ((u >> 16) & 1u);
  return (unsigned short)(r >> 16);
}
__device__ __forceinline__ float bf2f(unsigned short h) {
  return __uint_as_float((unsigned)h << 16);
}

// DPP row-rotate add: sums within each 16-lane row after ror 8,4,2,1.
template <int CTRL>
__device__ __forceinline__ float dpp_add(float s) {
  int t = __builtin_amdgcn_update_dpp(0, __float_as_int(s), CTRL, 0xf, 0xf, false);
  return s + __int_as_float(t);
}

// async global->LDS, 16B per lane; lds ptr must be wave-uniform.
__device__ __forceinline__ void gload16(const void* g, void* l) {
  __builtin_amdgcn_global_load_lds((const __attribute__((address_space(1))) void*)g,
                                   (__attribute__((address_space(3))) void*)l, 16, 0, 0);
}

// ---------------- fused A: bhist [0,64) | score_cast [64,64+NS) |
// lin1cast [64+NS, 64+NS+512). Private-row bhist: plain stores, no zeroing.
__global__ __launch_bounds__(256) void fusedA_kernel(const float* __restrict__ x,
                                                     const float* __restrict__ p,
                                                     float* __restrict__ score,
                                                     unsigned short* __restrict__ xh, int N, int NS,
                                                     const int* __restrict__ ei,
                                                     const int* __restrict__ ewi,
                                                     int* __restrict__ bh1p,
                                                     int* __restrict__ bh2p, int E,
                                                     const float* __restrict__ lin1,
                                                     unsigned short* __restrict__ WAB) {
  int tid = threadIdx.x;
  int b = blockIdx.x;
  if (b < 64) {
    // bucket histogram, LDS-aggregated, private row per block (64 rows)
    __shared__ int c1[128], c2[128];
    if (tid < 128) { c1[tid] = 0; c2[tid] = 0; }
    __syncthreads();
    int idx = b * 256 + tid;
    int stride = 64 * 256;
    for (int e = idx; e < E; e += stride) {
      atomicAdd(&c1[ei[E + e] >> WSHIFT], 1);
      atomicAdd(&c2[ewi[e] >> WSHIFT], 1);
    }
    __syncthreads();
    if (tid < 128) {
      bh1p[b * 128 + tid] = c1[tid];
      bh2p[b * 128 + tid] = c2[tid];
    }
  } else if (b < 64 + NS) {
    // score (incl. ||p||) + bf16 cast of x in one pass (x read once)
    int node = (b - 64) * 4 + (tid >> 6);
    int lane = tid & 63;
    if (node >= N) return;
    float4 xv = ((const float4*)(x + (size_t)node * 256))[lane];
    ushort4 hv;
    hv.x = f2bf(xv.x);
    hv.y = f2bf(xv.y);
    hv.z = f2bf(xv.z);
    hv.w = f2bf(xv.w);
    ((ushort4*)(xh + (size_t)node * 256))[lane] = hv;
    float4 pv = ((const float4*)p)[lane];
    float s = xv.x * pv.x + xv.y * pv.y + xv.z * pv.z + xv.w * pv.w;
    float sp = pv.x * pv.x + pv.y * pv.y + pv.z * pv.z + pv.w * pv.w;
#pragma unroll
    for (int off = 32; off > 0; off >>= 1) {
      s += __shfl_down(s, off, 64);
      sp += __shfl_down(sp, off, 64);
    }
    if (lane == 0) score[node] = s / sqrtf(sp);
  } else {
    // lin1_w [256][512] -> stacked BT (WA rows 0..255, WB rows 256..511)
    int idx = (b - 64 - NS) * 256 + tid;
    int n = idx >> 9, k = idx & 511;
    unsigned short h = f2bf(lin1[idx]);
    if (k < 256)
      WAB[n * 256 + k] = h;
    else
      WAB[(256 + n) * 256 + (k - 256)] = h;
  }
}

// ---------------- fused B: hist12 private rows (blocks 0..63) || bucket_scan
__global__ __launch_bounds__(256) void fusedB_kernel(const float* __restrict__ score, int n,
                                                     int* __restrict__ ghp,
                                                     const int* __restrict__ bh1p,
                                                     const int* __restrict__ bh2p,
                                                     int* __restrict__ bbase1,
                                                     int* __restrict__ bbase2,
                                                     int* __restrict__ gcur1,
                                                     int* __restrict__ gcur2,
                                                     int* __restrict__ rowp1,
                                                     int* __restrict__ rowp2, int N, int E) {
  int tid = threadIdx.x;
  if (blockIdx.x < 64) {
    // LDS-aggregated 4096-bin histogram, private row per block (no zeroing)
    __shared__ int lh[4096];
    for (int i = tid; i < 4096; i += 256) lh[i] = 0;
    __syncthreads();
    int idx = blockIdx.x * 256 + tid;
    int stride = 64 * 256;
    for (int i = idx; i < n; i += stride) {
      unsigned key = f2key(score[i]);
      atomicAdd(&lh[key >> 20], 1);
    }
    __syncthreads();
    int* row = ghp + blockIdx.x * 4096;
    for (int i = tid; i < 4096; i += 256) row[i] = lh[i];
  } else {
    // bucket scan: 2-way-parallel row sums (64 rows) -> bases + cursors
    __shared__ int ss[128];
    __shared__ int pp[256];
    int bk = tid & 127, hf = tid >> 7;
    // CSR1
    {
      int vp = 0;
      if (bk < NBUCK)
        for (int r = hf * 32; r < hf * 32 + 32; ++r) vp += bh1p[r * 128 + bk];
      pp[tid] = vp;
    }
    __syncthreads();
    int v = 0;
    if (tid < 128) { v = pp[tid] + pp[tid + 128]; ss[tid] = v; }
    __syncthreads();
    for (int off = 1; off < 128; off <<= 1) {
      int a = 0, bsum = 0;
      if (tid < 128) { a = ss[tid]; bsum = (tid >= off) ? ss[tid - off] : 0; }
      __syncthreads();
      if (tid < 128) ss[tid] = a + bsum;
      __syncthreads();
    }
    if (tid < 128) {
      int excl = ss[tid] - v;
      if (tid < NBUCK) { bbase1[tid] = excl; gcur1[tid] = excl; }
      if (tid == NBUCK - 1) bbase1[NBUCK] = excl + v;
    }
    __syncthreads();
    // CSR2
    {
      int vp = 0;
      if (bk < NBUCK)
        for (int r = hf * 32; r < hf * 32 + 32; ++r) vp += bh2p[r * 128 + bk];
      pp[tid] = vp;
    }
    __syncthreads();
    int v2 = 0;
    if (tid < 128) { v2 = pp[tid] + pp[tid + 128]; ss[tid] = v2; }
    __syncthreads();
    for (int off = 1; off < 128; off <<= 1) {
      int a = 0, bsum = 0;
      if (tid < 128) { a = ss[tid]; bsum = (tid >= off) ? ss[tid - off] : 0; }
      __syncthreads();
      if (tid < 128) ss[tid] = a + bsum;
      __syncthreads();
    }
    if (tid < 128) {
      int excl = ss[tid] - v2;
      if (tid < NBUCK) { bbase2[tid] = excl; gcur2[tid] = excl; }
      if (tid == NBUCK - 1) bbase2[NBUCK] = excl + v2;
    }
    if (tid == 0) { rowp1[N] = E; rowp2[N] = E; }
  }
}

// ---------------- fused C (1024 thr): p1 conv [0,nb) | p1 dec [nb,2nb) |
// topk (block 2nb). p1: tile-ranked scatter, 8192 edges/block, 8/thread.
__global__ __launch_bounds__(1024) void fusedC_kernel(const int* __restrict__ ei,
                                                      const float* __restrict__ attr,
                                                      int* __restrict__ gcur1,
                                                      int2* __restrict__ stage1,
                                                      const int* __restrict__ ewi,
                                                      int* __restrict__ gcur2,
                                                      int2* __restrict__ stage2,
                                                      int E, int nb,
                                                      const float* __restrict__ score, int n, int k,
                                                      const int* __restrict__ ghp,
                                                      int* __restrict__ perm,
                                                      float* __restrict__ tts) {
  int tid = threadIdx.x;
  if ((int)blockIdx.x < 2 * nb) {
    bool conv = (int)blockIdx.x < nb;
    __shared__ int pcnt[128], pcur[128];
    int base = (conv ? blockIdx.x : blockIdx.x - nb) * 8192;
    int* gcur = conv ? gcur1 : gcur2;
    int2* stage = conv ? stage1 : stage2;
    if (tid < 128) pcnt[tid] = 0;
    __syncthreads();
    int bk[8];
    int2 pl[8];
#pragma unroll
    for (int i = 0; i < 8; ++i) {
      int e = base + i * 1024 + tid;
      bk[i] = -1;
      if (e < E) {
        if (conv) {
          int d = ei[E + e];
          int s = ei[e];
          bk[i] = d >> WSHIFT;
          pl[i] = make_int2(s | ((d & WMASK) << 16), __float_as_int(attr[e]));
        } else {
          int s = ewi[e];
          int d = ewi[E + e];
          bk[i] = s >> WSHIFT;
          pl[i] = make_int2(d | ((s & WMASK) << 16), e);
        }
        atomicAdd(&pcnt[bk[i]], 1);
      }
    }
    __syncthreads();
    if (tid < NBUCK) {
      int c = pcnt[tid];
      pcur[tid] = c ? atomicAdd(&gcur[tid], c) : 0;
    }
    __syncthreads();
#pragma unroll
    for (int i = 0; i < 8; ++i) {
      if (bk[i] >= 0) {
        int pos = atomicAdd(&pcur[bk[i]], 1);
        stage[pos] = pl[i];
      }
    }
  } else {
    // top-k: suffix-scan threshold (over 64 private rows) + collect + sort
    __shared__ int part[1024];
    __shared__ unsigned sT;
    int s0, s1, s2, s3;
    {
      int b0 = tid * 4;
      s0 = 0; s1 = 0; s2 = 0; s3 = 0;
      for (int r = 0; r < 64; ++r) {
        int4 v4 = *(const int4*)(ghp + r * 4096 + b0);
        s0 += v4.x; s1 += v4.y; s2 += v4.z; s3 += v4.w;
      }
      part[tid] = s0 + s1 + s2 + s3;
      __syncthreads();
      for (int off = 1; off < 1024; off <<= 1) {
        int v = part[tid];
        int add = (tid + off < 1024) ? part[tid + off] : 0;
        __syncthreads();
        part[tid] = v + add;
        __syncthreads();
      }
      int sufChunk = part[tid];
      int sufNext = (tid < 1023) ? part[tid + 1] : 0;
      if (sufNext < k && sufChunk >= k) {
        int run = sufNext;
        int b;
        run += s3;
        if (run >= k) b = tid * 4 + 3;
        else {
          run += s2;
          if (run >= k) b = tid * 4 + 2;
          else {
            run += s1;
            b = (run >= k) ? tid * 4 + 1 : tid * 4;
          }
        }
        sT = ((unsigned)b) << 20;
      }
    }
    __syncthreads();
    unsigned T = sT;
    __shared__ unsigned keys[1024];
    __shared__ int idxs[1024];
    __shared__ int cnt;
    if (tid == 0) cnt = 0;
    keys[tid] = 0u;
    idxs[tid] = 0x7fffffff;
    __syncthreads();
    for (int i = tid; i < n; i += 1024) {
      unsigned key = f2key(score[i]);
      if (key >= T) {
        int p = atomicAdd(&cnt, 1);
        if (p < 1024) { keys[p] = key; idxs[p] = i; }
      }
    }
    __syncthreads();
    for (int size = 2; size <= 1024; size <<= 1) {
      for (int stride = size >> 1; stride > 0; stride >>= 1) {
        int j = tid ^ stride;
        if (j > tid) {
          unsigned ka = keys[tid], kb = keys[j];
          int ia = idxs[tid], ib = idxs[j];
          bool aBefore = (ka > kb) || (ka == kb && ia < ib);
          bool up = ((tid & size) == 0);
          if (aBefore != up) {
            keys[tid] = kb; keys[j] = ka;
            idxs[tid] = ib; idxs[j] = ia;
          }
        }
        __syncthreads();
      }
    }
    if (tid < k) {
      int idx = idxs[tid];
      perm[tid] = idx;
      tts[tid] = tanhf(score[idx]);
    }
  }
}

// ---------------- fused D (256 thr): gru (blocks 0..255) || p2 (256..451) --
// gru writes evolved W TRANSPOSED bf16: WevoT[n*256+k] = W[k][n] (B^T layout
// for GEMM1).
__global__ __launch_bounds__(256) void fusedD_kernel(const float* __restrict__ x,
                                                     const int* __restrict__ perm,
                                                     const float* __restrict__ tts,
                                                     const float* __restrict__ Wi,
                                                     const float* __restrict__ W_ih,
                                                     const float* __restrict__ W_hh,
                                                     const float* __restrict__ b_ih,
                                                     const float* __restrict__ b_hh,
                                                     unsigned short* __restrict__ WevoT,
                                                     const int2* __restrict__ stage1,
                                                     const int* __restrict__ bbase1,
                                                     int2* __restrict__ esv,
                                                     int* __restrict__ rowp1,
                                                     float* __restrict__ dinv,
                                                     const int2* __restrict__ stage2,
                                                     const int* __restrict__ bbase2,
                                                     int2* __restrict__ eto,
                                                     int* __restrict__ rowp2, int N) {
  int tid = threadIdx.x;
  if (blockIdx.x < 256) {
    // GRU step with x_tilde inline
    int i = blockIdx.x, j = tid;
    __shared__ float sx[256], sh[256];
    sx[j] = x[(size_t)perm[i] * 256 + j] * tts[i];
    sh[j] = Wi[i * 256 + j];
    __syncthreads();
    float gi[3], gh[3];
#pragma unroll
    for (int g = 0; g < 3; ++g) {
      int row = g * 256 + j;
      const float4* wi4 = (const float4*)(W_ih + (size_t)row * 256);
      const float4* wh4 = (const float4*)(W_hh + (size_t)row * 256);
      float si = 0.f, s2 = 0.f;
      for (int k4 = 0; k4 < 64; ++k4) {
        float4 wv = wi4[k4];
        float4 hv = wh4[k4];
        int k = k4 * 4;
        si += sx[k] * wv.x + sx[k + 1] * wv.y + sx[k + 2] * wv.z + sx[k + 3] * wv.w;
        s2 += sh[k] * hv.x + sh[k + 1] * hv.y + sh[k + 2] * hv.z + sh[k + 3] * hv.w;
      }
      gi[g] = si + b_ih[row];
      gh[g] = s2 + b_hh[row];
    }
    float r = 1.f / (1.f + expf(-(gi[0] + gh[0])));
    float z = 1.f / (1.f + expf(-(gi[1] + gh[1])));
    float nn = tanhf(gi[2] + r * gh[2]);
    float w = (1.f - z) * nn + z * sh[j];
    WevoT[(size_t)j * 256 + i] = f2bf(w);
  } else {
    // p2: per-bucket node histogram + scan + node-ordered CSR write
    __shared__ int cnt[512];
    __shared__ float degs[512];
    __shared__ int pref[512];
    __shared__ int ss[256];
    int bb2 = blockIdx.x - 256;
    bool isConv = bb2 < NBUCK;
    int b = isConv ? bb2 : bb2 - NBUCK;
    const int2* stage = isConv ? stage1 : stage2;
    const int* bbase = isConv ? bbase1 : bbase2;
    int beg = bbase[b], end = bbase[b + 1];
    int node0 = b << WSHIFT;
    cnt[tid] = 0; cnt[tid + 256] = 0;
    degs[tid] = 0.f; degs[tid + 256] = 0.f;
    __syncthreads();
    for (int j = beg + tid; j < end; j += 256) {
      int2 p = stage[j];
      int loc = p.x >> 16;
      atomicAdd(&cnt[loc], 1);
      if (isConv) atomicAdd(&degs[loc], __int_as_float(p.y));
    }
    __syncthreads();
    int c0 = cnt[2 * tid], c1 = cnt[2 * tid + 1];
    ss[tid] = c0 + c1;
    __syncthreads();
    for (int off = 1; off < 256; off <<= 1) {
      int a = ss[tid];
      int bsum = (tid >= off) ? ss[tid - off] : 0;
      __syncthreads();
      ss[tid] = a + bsum;
      __syncthreads();
    }
    int excl = (tid ? ss[tid - 1] : 0);
    pref[2 * tid] = excl;
    pref[2 * tid + 1] = excl + c0;
    __syncthreads();
#pragma unroll
    for (int h = 0; h < 2; ++h) {
      int i = tid + h * 256;
      int node = node0 + i;
      if (node < N) {
        if (isConv) {
          rowp1[node] = beg + pref[i];
          float d = degs[i];
          dinv[node] = d > 0.f ? 1.f / sqrtf(d) : 0.f;
        } else {
          rowp2[node] = beg + pref[i];
        }
      }
    }
    __syncthreads();
    int2* outb = isConv ? esv : eto;
    for (int j = beg + tid; j < end; j += 256) {
      int2 p = stage[j];
      int loc = p.x >> 16;
      int pos = beg + atomicAdd(&pref[loc], 1);
      outb[pos] = make_int2(p.x & 0xFFFF, p.y);
    }
  }
}

// ---------------------------------------------------------------------------
// m97-structure bf16 MFMA GEMM: per blockIdx.y,
//   C[M,256] = A[M,256] @ (BT[by*256 .. by*256+255][256])^T   (bf16 in/out)
// 128x256 tile, 8 waves, BK=32, global_load_lds staging, 2-barrier K-loop.
// ---------------------------------------------------------------------------
__global__ __launch_bounds__(512) void mfma_gemm128(const unsigned short* __restrict__ A,
                                                    const unsigned short* __restrict__ BT,
                                                    unsigned short* __restrict__ C1,
                                                    unsigned short* __restrict__ C2,
                                                    int M) {
  __shared__ unsigned short sA[128 * 32];
  __shared__ unsigned short sB[256 * 32];
  int tid = threadIdx.x;
  int wave = tid >> 6, lane = tid & 63;
  int quad = lane >> 4, r16 = lane & 15;
  int wm = wave >> 2, wn = wave & 3;
  int mbase = blockIdx.x * 128;
  const unsigned short* Bt = BT + ((size_t)blockIdx.y << 16);
  unsigned short* Cout = blockIdx.y ? C2 : C1;

  int srow = tid >> 2, scolq = tid & 3;
  const unsigned short* gA = A + (size_t)(mbase + srow) * 256 + scolq * 8;
  const unsigned short* gB0 = Bt + (size_t)srow * 256 + scolq * 8;
  const unsigned short* gB1 = Bt + (size_t)(128 + srow) * 256 + scolq * 8;
  unsigned short* lA = sA + wave * 512;
  unsigned short* lB0 = sB + wave * 512;
  unsigned short* lB1 = sB + 4096 + wave * 512;

  f32x4 acc[4][4];
#pragma unroll
  for (int i = 0; i < 4; ++i)
#pragma unroll
    for (int j = 0; j < 4; ++j) acc[i][j] = (f32x4){0.f, 0.f, 0.f, 0.f};

  const unsigned short* pA = sA + (wm * 64 + r16) * 32 + quad * 8;
  const unsigned short* pB = sB + (wn * 64 + r16) * 32 + quad * 8;

  for (int k0 = 0; k0 < 256; k0 += 32) {
    if (k0) __syncthreads();
    gload16(gA + k0, lA);
    gload16(gB0 + k0, lB0);
    gload16(gB1 + k0, lB1);
    __syncthreads();
    bf16x8 af[4], bfr[4];
#pragma unroll
    for (int mt = 0; mt < 4; ++mt) af[mt] = *(const bf16x8*)(pA + mt * 512);
#pragma unroll
    for (int nt = 0; nt < 4; ++nt) bfr[nt] = *(const bf16x8*)(pB + nt * 512);
#pragma unroll
    for (int mt = 0; mt < 4; ++mt)
#pragma unroll
      for (int nt = 0; nt < 4; ++nt)
        acc[mt][nt] = __builtin_amdgcn_mfma_f32_16x16x32_bf16(af[mt], bfr[nt], acc[mt][nt], 0, 0, 0);
  }
#pragma unroll
  for (int mt = 0; mt < 4; ++mt) {
#pragma unroll
    for (int rr = 0; rr < 4; ++rr) {
      int grow = mbase + wm * 64 + mt * 16 + quad * 4 + rr;
      if (grow < M) {
#pragma unroll
        for (int nt = 0; nt < 4; ++nt)
          Cout[(size_t)grow * 256 + wn * 64 + nt * 16 + r16] = f2bf(acc[mt][nt][rr]);
      }
    }
  }
}

// one wave per dst node, quad decomposition: 16 lanes/edge x 4 edges/group.
// Per 64-edge chunk: lane l coalesced-loads meta esv[cb+l] and applies
// dinv[src] once (L2-resident), then stage refills broadcast src/v via shfl
// (refill chain rows-only). 3-stage in-place prefetch.
__global__ __launch_bounds__(256) void gcn_gather(const unsigned short* __restrict__ xw,
                                                  const int* __restrict__ row_ptr,
                                                  const int2* __restrict__ esv,
                                                  const float* __restrict__ dinv,
                                                  unsigned short* __restrict__ ne, int N) {
  int node = blockIdx.x * 4 + (threadIdx.x >> 6);
  int lane = threadIdx.x & 63;
  int g = lane & 15, q = lane >> 4;
  if (node >= N) return;
  int beg = row_ptr[node], end = row_ptr[node + 1];
  float acc[16];
#pragma unroll
  for (int c = 0; c < 16; ++c) acc[c] = 0.f;
  const unsigned short* xb = xw + g * 16;

  for (int cb = beg; cb < end; cb += 64) {
    int cend = cb + 64 < end ? cb + 64 : end;
    int me = cb + lane;
    int2 mm = (me < cend) ? esv[me] : make_int2(0, 0);
    int mx = mm.x;
    float mv = __int_as_float(mm.y) * dinv[mx];

    float vA = 0.f, vB = 0.f, vC = 0.f;
    u16x8 rAa, rAb, rBa, rBb, rCa, rCb;
    {
      int e = cb + q;
      int sx = __shfl(mx, q, 64);
      float tv = __shfl(mv, q, 64);
      vA = (e < cend) ? tv : 0.f;
      rAa = *(const u16x8*)(xb + (size_t)sx * 256);
      rAb = *(const u16x8*)(xb + (size_t)sx * 256 + 8);
    }
    if (cb + 4 < cend) {
      int e = cb + 4 + q;
      int sx = __shfl(mx, 4 + q, 64);
      float tv = __shfl(mv, 4 + q, 64);
      vB = (e < cend) ? tv : 0.f;
      rBa = *(const u16x8*)(xb + (size_t)sx * 256);
      rBb = *(const u16x8*)(xb + (size_t)sx * 256 + 8);
    } else { rBa = rAa; rBb = rAb; }
    if (cb + 8 < cend) {
      int e = cb + 8 + q;
      int sx = __shfl(mx, 8 + q, 64);
      float tv = __shfl(mv, 8 + q, 64);
      vC = (e < cend) ? tv : 0.f;
      rCa = *(const u16x8*)(xb + (size_t)sx * 256);
      rCb = *(const u16x8*)(xb + (size_t)sx * 256 + 8);
    } else { rCa = rAa; rCb = rAb; }

    for (int jb = cb; jb < cend; jb += 12) {
      // consume A, refill A <- jb+12
#pragma unroll
      for (int c = 0; c < 8; ++c) acc[c] += bf2f(rAa[c]) * vA;
#pragma unroll
      for (int c = 0; c < 8; ++c) acc[8 + c] += bf2f(rAb[c]) * vA;
      vA = 0.f;
      if (jb + 12 < cend) {
        int e = jb + 12 + q;
        int idx = (e - cb) & 63;
        int sx = __shfl(mx, idx, 64);
        float tv = __shfl(mv, idx, 64);
        vA = (e < cend) ? tv : 0.f;
        rAa = *(const u16x8*)(xb + (size_t)sx * 256);
        rAb = *(const u16x8*)(xb + (size_t)sx * 256 + 8);
      }
      // consume B, refill B <- jb+16
#pragma unroll
      for (int c = 0; c < 8; ++c) acc[c] += bf2f(rBa[c]) * vB;
#pragma unroll
      for (int c = 0; c < 8; ++c) acc[8 + c] += bf2f(rBb[c]) * vB;
      vB = 0.f;
      if (jb + 16 < cend) {
        int e = jb + 16 + q;
        int idx = (e - cb) & 63;
        int sx = __shfl(mx, idx, 64);
        float tv = __shfl(mv, idx, 64);
        vB = (e < cend) ? tv : 0.f;
        rBa = *(const u16x8*)(xb + (size_t)sx * 256);
        rBb = *(const u16x8*)(xb + (size_t)sx * 256 + 8);
      }
      // consume C, refill C <- jb+20
#pragma unroll
      for (int c = 0; c < 8; ++c) acc[c] += bf2f(rCa[c]) * vC;
#pragma unroll
      for (int c = 0; c < 8; ++c) acc[8 + c] += bf2f(rCb[c]) * vC;
      vC = 0.f;
      if (jb + 20 < cend) {
        int e = jb + 20 + q;
        int idx = (e - cb) & 63;
        int sx = __shfl(mx, idx, 64);
        float tv = __shfl(mv, idx, 64);
        vC = (e < cend) ? tv : 0.f;
        rCa = *(const u16x8*)(xb + (size_t)sx * 256);
        rCb = *(const u16x8*)(xb + (size_t)sx * 256 + 8);
      }
    }
  }
  // cross-quad combine (each quad holds a partial over the same channels)
#pragma unroll
  for (int c = 0; c < 16; ++c) {
    acc[c] += __shfl_xor(acc[c], 16, 64);
    acc[c] += __shfl_xor(acc[c], 32, 64);
  }
  if (q == 0) {
    float dd = dinv[node];
    u16x8 o0, o1;
#pragma unroll
    for (int c = 0; c < 8; ++c) {
      o0[c] = f2bf(acc[c] * dd);
      o1[c] = f2bf(acc[8 + c] * dd);
    }
    *(u16x8*)(ne + (size_t)node * 256 + g * 16) = o0;
    *(u16x8*)(ne + (size_t)node * 256 + g * 16 + 8) = o1;
  }
}

// decode grouped by src, one wave per node, quad decomposition. Per-chunk
// meta preload + shfl broadcast; 3-stage in-place prefetch; DPP row_ror
// reduce. A[s]+b1 and w2 register-resident per lane (16 channels).
__global__ __launch_bounds__(256) void edge_decode_csr(const unsigned short* __restrict__ A,
                                                       const unsigned short* __restrict__ Bm,
                                                       const int* __restrict__ row_ptr,
                                                       const int2* __restrict__ eto,
                                                       const float* __restrict__ b1,
                                                       const float* __restrict__ w2,
                                                       const float* __restrict__ b2,
                                                       float* __restrict__ out, int N) {
  int node = blockIdx.x * 4 + (threadIdx.x >> 6);
  int lane = threadIdx.x & 63;
  int g = lane & 15, q = lane >> 4;
  if (node >= N) return;
  int beg = row_ptr[node], end = row_ptr[node + 1];
  if (beg >= end) return;
  float a[16], w[16];
  {
    u16x8 a0 = *(const u16x8*)(A + (size_t)node * 256 + g * 16);
    u16x8 a1 = *(const u16x8*)(A + (size_t)node * 256 + g * 16 + 8);
    const float4* bp = (const float4*)(b1 + g * 16);
    const float4* wp = (const float4*)(w2 + g * 16);
#pragma unroll
    for (int i = 0; i < 4; ++i) {
      float4 bv = bp[i];
      float4 wv = wp[i];
      a[i * 4 + 0] = (i < 2 ? bf2f(a0[i * 4 + 0]) : bf2f(a1[i * 4 - 8])) + bv.x;
      a[i * 4 + 1] = (i < 2 ? bf2f(a0[i * 4 + 1]) : bf2f(a1[i * 4 - 7])) + bv.y;
      a[i * 4 + 2] = (i < 2 ? bf2f(a0[i * 4 + 2]) : bf2f(a1[i * 4 - 6])) + bv.z;
      a[i * 4 + 3] = (i < 2 ? bf2f(a0[i * 4 + 3]) : bf2f(a1[i * 4 - 5])) + bv.w;
      w[i * 4 + 0] = wv.x;
      w[i * 4 + 1] = wv.y;
      w[i * 4 + 2] = wv.z;
      w[i * 4 + 3] = wv.w;
    }
  }
  float base = b2[0];
  const unsigned short* Bb = Bm + g * 16;

  for (int cb = beg; cb < end; cb += 64) {
    int cend = cb + 64 < end ? cb + 64 : end;
    int me = cb + lane;
    int2 mm = (me < cend) ? eto[me] : make_int2(0, 0);
    int mx = mm.x, my = mm.y;

    bool okA = false, okB = false, okC = false;
    int oA = 0, oB = 0, oC = 0;
    u16x8 rAa, rAb, rBa, rBb, rCa, rCb;
    {
      int e = cb + q;
      int sx = __shfl(mx, q, 64);
      oA = __shfl(my, q, 64);
      okA = e < cend;
      rAa = *(const u16x8*)(Bb + (size_t)sx * 256);
      rAb = *(const u16x8*)(Bb + (size_t)sx * 256 + 8);
    }
    if (cb + 4 < cend) {
      int e = cb + 4 + q;
      int sx = __shfl(mx, 4 + q, 64);
      oB = __shfl(my, 4 + q, 64);
      okB = e < cend;
      rBa = *(const u16x8*)(Bb + (size_t)sx * 256);
      rBb = *(const u16x8*)(Bb + (size_t)sx * 256 + 8);
    } else { rBa = rAa; rBb = rAb; }
    if (cb + 8 < cend) {
      int e = cb + 8 + q;
      int sx = __shfl(mx, 8 + q, 64);
      oC = __shfl(my, 8 + q, 64);
      okC = e < cend;
      rCa = *(const u16x8*)(Bb + (size_t)sx * 256);
      rCb = *(const u16x8*)(Bb + (size_t)sx * 256 + 8);
    } else { rCa = rAa; rCb = rAb; }

    for (int jb = cb; jb < cend; jb += 12) {
      // consume A
      {
        float s0 = 0.f, s1 = 0.f;
#pragma unroll
        for (int c = 0; c < 8; ++c) s0 += fmaxf(a[c] + bf2f(rAa[c]), 0.f) * w[c];
#pragma unroll
        for (int c = 0; c < 8; ++c) s1 += fmaxf(a[8 + c] + bf2f(rAb[c]), 0.f) * w[8 + c];
        float s = s0 + s1;
        s = dpp_add<0x128>(s);  // row_ror:8
        s = dpp_add<0x124>(s);  // row_ror:4
        s = dpp_add<0x122>(s);  // row_ror:2
        s = dpp_add<0x121>(s);  // row_ror:1
        if (g == 0 && okA) out[oA] = s + base;
      }
      // refill A <- jb+12
      okA = false;
      if (jb + 12 < cend) {
        int e = jb + 12 + q;
        int idx = (e - cb) & 63;
        int sx = __shfl(mx, idx, 64);
        oA = __shfl(my, idx, 64);
        okA = e < cend;
        rAa = *(const u16x8*)(Bb + (size_t)sx * 256);
        rAb = *(const u16x8*)(Bb + (size_t)sx * 256 + 8);
      }
      // consume B
      {
        float s0 = 0.f, s1 = 0.f;
#pragma unroll
        for (int c = 0; c < 8; ++c) s0 += fmaxf(a[c] + bf2f(rBa[c]), 0.f) * w[c];
#pragma unroll
        for (int c = 0; c < 8; ++c) s1 += fmaxf(a[8 + c] + bf2f(rBb[c]), 0.f) * w[8 + c];
        float s = s0 + s1;
        s = dpp_add<0x128>(s);
        s = dpp_add<0x124>(s);
        s = dpp_add<0x122>(s);
        s = dpp_add<0x121>(s);
        if (g == 0 && okB) out[oB] = s + base;
      }
      // refill B <- jb+16
      okB = false;
      if (jb + 16 < cend) {
        int e = jb + 16 + q;
        int idx = (e - cb) & 63;
        int sx = __shfl(mx, idx, 64);
        oB = __shfl(my, idx, 64);
        okB = e < cend;
        rBa = *(const u16x8*)(Bb + (size_t)sx * 256);
        rBb = *(const u16x8*)(Bb + (size_t)sx * 256 + 8);
      }
      // consume C
      {
        float s0 = 0.f, s1 = 0.f;
#pragma unroll
        for (int c = 0; c < 8; ++c) s0 += fmaxf(a[c] + bf2f(rCa[c]), 0.f) * w[c];
#pragma unroll
        for (int c = 0; c < 8; ++c) s1 += fmaxf(a[8 + c] + bf2f(rCb[c]), 0.f) * w[8 + c];
        float s = s0 + s1;
        s = dpp_add<0x128>(s);
        s = dpp_add<0x124>(s);
        s = dpp_add<0x122>(s);
        s = dpp_add<0x121>(s);
        if (g == 0 && okC) out[oC] = s + base;
      }
      // refill C <- jb+20
      okC = false;
      if (jb + 20 < cend) {
        int e = jb + 20 + q;
        int idx = (e - cb) & 63;
        int sx = __shfl(mx, idx, 64);
        oC = __shfl(my, idx, 64);
        okC = e < cend;
        rCa = *(const u16x8*)(Bb + (size_t)sx * 256);
        rCb = *(const u16x8*)(Bb + (size_t)sx * 256 + 8);
      }
    }
  }
}

extern "C" void kernel_launch(void* const* d_in, const int* in_sizes, int n_in,
                              void* d_out, int out_size, void* d_ws, size_t ws_size,
                              hipStream_t stream) {
  const float* x      = (const float*)d_in[0];
  const int*   ei     = (const int*)d_in[1];
  const float* attr   = (const float*)d_in[2];
  const int*   ewi    = (const int*)d_in[3];
  const float* p_pool = (const float*)d_in[4];
  const float* W_ih   = (const float*)d_in[5];
  const float* W_hh   = (const float*)d_in[6];
  const float* b_ih   = (const float*)d_in[7];
  const float* b_hh   = (const float*)d_in[8];
  const float* W_init = (const float*)d_in[9];
  const float* lin1_w = (const float*)d_in[10];
  const float* lin1_b = (const float*)d_in[11];
  const float* lin2_w = (const float*)d_in[12];
  const float* lin2_b = (const float*)d_in[13];
  float* out = (float*)d_out;

  const int C = 256;
  const int N = in_sizes[0] / C;   // 50000
  const int E = in_sizes[2];       // 800000

  // ---- workspace layout (256B aligned) ----
  char* ws = (char*)d_ws;
  size_t off = 0;
  auto alloc = [&](size_t bytes) {
    size_t o = off;
    off = (off + bytes + 255) & ~(size_t)255;
    return o;
  };
  float*          score  = (float*)(ws + alloc((size_t)N * 4));
  int*            perm   = (int*)(ws + alloc(C * 4));
  float*          tts    = (float*)(ws + alloc(C * 4));
  unsigned short* WevoT  = (unsigned short*)(ws + alloc((size_t)C * C * 2));
  unsigned short* WAB    = (unsigned short*)(ws + alloc((size_t)2 * C * C * 2));
  int*            bh1p   = (int*)(ws + alloc((size_t)64 * 128 * 4));
  int*            bh2p   = (int*)(ws + alloc((size_t)64 * 128 * 4));
  int*            ghp    = (int*)(ws + alloc((size_t)64 * 4096 * 4));
  int*            bbase1 = (int*)(ws + alloc((NBUCK + 1) * 4));
  int*            bbase2 = (int*)(ws + alloc((NBUCK + 1) * 4));
  int*            gcur1  = (int*)(ws + alloc(128 * 4));
  int*            gcur2  = (int*)(ws + alloc(128 * 4));
  float*          dinv   = (float*)(ws + alloc((size_t)N * 4));
  int*            rowp1  = (int*)(ws + alloc((size_t)(N + 1) * 4));
  int*            rowp2  = (int*)(ws + alloc((size_t)(N + 1) * 4));
  int2*           stage1 = (int2*)(ws + alloc((size_t)E * 8));
  int2*           stage2 = (int2*)(ws + alloc((size_t)E * 8));
  int2*           esv    = (int2*)(ws + alloc((size_t)E * 8));
  int2*           eto    = (int2*)(ws + alloc((size_t)E * 8));
  unsigned short* xh     = (unsigned short*)(ws + alloc((size_t)N * C * 2));
  unsigned short* xwh    = (unsigned short*)(ws + alloc((size_t)N * C * 2));
  unsigned short* Bbf    = (unsigned short*)(ws + alloc((size_t)N * C * 2));
  // aliases (stream-ordered producers/consumers):
  unsigned short* ne  = xh;   // xh dead after GEMM1
  unsigned short* Abf = xwh;  // xwh dead after gather

  int NS = (N + 3) / 4;            // 12500 score blocks
  int nbP1 = (E + 8191) / 8192;    // 98 (1024-thread p1 blocks)

  // A) bhist [0,64) || score_cast [64,64+NS) || lin1cast [64+NS, +512)
  fusedA_kernel<<<64 + NS + 512, 256, 0, stream>>>(x, p_pool, score, xh, N, NS,
                                                   ei, ewi, bh1p, bh2p, E,
                                                   lin1_w, WAB);

  // B) hist12 private rows (64 blocks) || bucket_scan (block 64, 2-way sums)
  fusedB_kernel<<<65, 256, 0, stream>>>(score, N, ghp, bh1p, bh2p,
                                        bbase1, bbase2, gcur1, gcur2,
                                        rowp1, rowp2, N, E);

  // C) p1 conv+dec (2*98 blocks, 8192 edges each) || topk (block 196)
  fusedC_kernel<<<2 * nbP1 + 1, 1024, 0, stream>>>(ei, attr, gcur1, stage1,
                                                   ewi, gcur2, stage2, E, nbP1,
                                                   score, N, C, ghp, perm, tts);

  // D) gru (256 blocks, writes WevoT) || p2 (196 blocks)
  fusedD_kernel<<<256 + 2 * NBUCK, 256, 0, stream>>>(x, perm, tts, W_init,
                                                     W_ih, W_hh, b_ih, b_hh, WevoT,
                                                     stage1, bbase1, esv, rowp1, dinv,
                                                     stage2, bbase2, eto, rowp2, N);

  // E) xw = x @ Wevo (also acts as L2 prefetch for gather's random reads)
  mfma_gemm128<<<dim3((N + 127) / 128, 1), 512, 0, stream>>>(xh, WevoT, xwh, xwh, N);

  // F) gather (per-node waves; dinv applied at meta preload; xwh L2-warm)
  gcn_gather<<<NS, 256, 0, stream>>>(xwh, rowp1, esv, dinv, ne, N);

  // G) decoder projections: stacked BT (WA^T | WB^T), gridDim.y = 2
  mfma_gemm128<<<dim3((N + 127) / 128, 2), 512, 0, stream>>>(ne, WAB, Abf, Bbf, N);

  // H) edge decode (per-node waves, 3-stage prefetch + DPP reduce)
  edge_decode_csr<<<NS, 256, 0, stream>>>(Abf, Bbf, rowp2, eto,
                                          lin1_b, lin2_w, lin2_b, out, N);
}

// Round 14
// 414.707 us; speedup vs baseline: 1.0422x; 1.0422x over previous
//
#include <hip/hip_runtime.h>
#include <hip/hip_bf16.h>
#include <math.h>

// ---------------------------------------------------------------------------
// EvolveGCNH + GCNConv + EdgeDecoder.
// R1..R19: CSR bucket sort, quad gather/decode, MFMA GEMMs, meta preload,
//          co-launched chains (405.6 best; boundary ~12us/launch).
// R20-R23: algebraic reorder lineage never beat R19 (GEMM1 doubles as L2
//          prefetch for gather). R24: R19 structure + fusions = 432 BUT
//          exposed fusedD (gru||p2) = 69us @ VALU 9% / occ 17.5%:
//          gru's weight reads are 64-lanes-64-rows UNCOALESCED (each wave
//          load = 64 cache lines 1KB apart; ~98K line requests/block at
//          ~1 block/CU residency = tens of us of memory-issue serialization).
// R25 (this round): coalesce the GRU weight stream.
//   - fusedA +768 blocks: transpose+pack W_ih/W_hh -> WT2[p][r] =
//     (bf16 W[r][2p], bf16 W[r][2p+1])  ([128][768] uint, L2-resident).
//   - gru branch: thread j reads WT2[p*768+r] (lane-consecutive, coalesced);
//     128 iters x 3 gates; sx/sh LDS-broadcast. Only numeric change: GRU
//     weights bf16 (gates compressive; rest of pipeline already bf16).
// ---------------------------------------------------------------------------

typedef __attribute__((ext_vector_type(8))) short bf16x8;
typedef __attribute__((ext_vector_type(8))) unsigned short u16x8;
typedef __attribute__((ext_vector_type(4))) float f32x4;

#define WSHIFT 9              // 512 nodes per bucket
#define WMASK 511
#define NBUCK 98              // ceil(50000/512)

__device__ __forceinline__ unsigned f2key(float f) {
  unsigned u = __float_as_uint(f);
  return (u & 0x80000000u) ? ~u : (u | 0x80000000u);
}

// round-to-nearest-even fp32 -> bf16 bits
__device__ __forceinline__ unsigned short f2bf(float f) {
  unsigned u = __float_as_uint(f);
  unsigned r = u + 0x7fffu + ((u >> 16) & 1u);
  return (unsigned short)(r >> 16);
}
__device__ __forceinline__ float bf2f(unsigned short h) {
  return __uint_as_float((unsigned)h << 16);
}

// DPP row-rotate add: sums within each 16-lane row after ror 8,4,2,1.
template <int CTRL>
__device__ __forceinline__ float dpp_add(float s) {
  int t = __builtin_amdgcn_update_dpp(0, __float_as_int(s), CTRL, 0xf, 0xf, false);
  return s + __int_as_float(t);
}

// async global->LDS, 16B per lane; lds ptr must be wave-uniform.
__device__ __forceinline__ void gload16(const void* g, void* l) {
  __builtin_amdgcn_global_load_lds((const __attribute__((address_space(1))) void*)g,
                                   (__attribute__((address_space(3))) void*)l, 16, 0, 0);
}

// ---------------- fused A: bhist [0,64) | score_cast [64,64+NS) |
// lin1cast [64+NS, +512) | wT pack [64+NS+512, +768).
// Private-row bhist: plain stores, no zeroing.
__global__ __launch_bounds__(256) void fusedA_kernel(const float* __restrict__ x,
                                                     const float* __restrict__ p,
                                                     float* __restrict__ score,
                                                     unsigned short* __restrict__ xh, int N, int NS,
                                                     const int* __restrict__ ei,
                                                     const int* __restrict__ ewi,
                                                     int* __restrict__ bh1p,
                                                     int* __restrict__ bh2p, int E,
                                                     const float* __restrict__ lin1,
                                                     unsigned short* __restrict__ WAB,
                                                     const float* __restrict__ W_ih,
                                                     const float* __restrict__ W_hh,
                                                     unsigned* __restrict__ WihT2,
                                                     unsigned* __restrict__ WhhT2) {
  int tid = threadIdx.x;
  int b = blockIdx.x;
  if (b < 64) {
    // bucket histogram, LDS-aggregated, private row per block (64 rows)
    __shared__ int c1[128], c2[128];
    if (tid < 128) { c1[tid] = 0; c2[tid] = 0; }
    __syncthreads();
    int idx = b * 256 + tid;
    int stride = 64 * 256;
    for (int e = idx; e < E; e += stride) {
      atomicAdd(&c1[ei[E + e] >> WSHIFT], 1);
      atomicAdd(&c2[ewi[e] >> WSHIFT], 1);
    }
    __syncthreads();
    if (tid < 128) {
      bh1p[b * 128 + tid] = c1[tid];
      bh2p[b * 128 + tid] = c2[tid];
    }
  } else if (b < 64 + NS) {
    // score (incl. ||p||) + bf16 cast of x in one pass (x read once)
    int node = (b - 64) * 4 + (tid >> 6);
    int lane = tid & 63;
    if (node >= N) return;
    float4 xv = ((const float4*)(x + (size_t)node * 256))[lane];
    ushort4 hv;
    hv.x = f2bf(xv.x);
    hv.y = f2bf(xv.y);
    hv.z = f2bf(xv.z);
    hv.w = f2bf(xv.w);
    ((ushort4*)(xh + (size_t)node * 256))[lane] = hv;
    float4 pv = ((const float4*)p)[lane];
    float s = xv.x * pv.x + xv.y * pv.y + xv.z * pv.z + xv.w * pv.w;
    float sp = pv.x * pv.x + pv.y * pv.y + pv.z * pv.z + pv.w * pv.w;
#pragma unroll
    for (int off = 32; off > 0; off >>= 1) {
      s += __shfl_down(s, off, 64);
      sp += __shfl_down(sp, off, 64);
    }
    if (lane == 0) score[node] = s / sqrtf(sp);
  } else if (b < 64 + NS + 512) {
    // lin1_w [256][512] -> stacked BT (WA rows 0..255, WB rows 256..511)
    int idx = (b - 64 - NS) * 256 + tid;
    int n = idx >> 9, k = idx & 511;
    unsigned short h = f2bf(lin1[idx]);
    if (k < 256)
      WAB[n * 256 + k] = h;
    else
      WAB[(256 + n) * 256 + (k - 256)] = h;
  } else {
    // transpose+pack GRU weights: WT2[p*768 + r] = (bf16 W[r][2p], W[r][2p+1])
    int idx = (b - 64 - NS - 512) * 256 + tid;   // [0, 196608)
    int m = idx >= 98304;
    int id2 = idx - m * 98304;
    int r = id2 >> 7, pp = id2 & 127;
    const float* W = m ? W_hh : W_ih;
    unsigned* WT = m ? WhhT2 : WihT2;
    float w0 = W[(size_t)r * 256 + 2 * pp];
    float w1 = W[(size_t)r * 256 + 2 * pp + 1];
    WT[pp * 768 + r] = (unsigned)f2bf(w0) | ((unsigned)f2bf(w1) << 16);
  }
}

// ---------------- fused B: hist12 private rows (blocks 0..63) || bucket_scan
__global__ __launch_bounds__(256) void fusedB_kernel(const float* __restrict__ score, int n,
                                                     int* __restrict__ ghp,
                                                     const int* __restrict__ bh1p,
                                                     const int* __restrict__ bh2p,
                                                     int* __restrict__ bbase1,
                                                     int* __restrict__ bbase2,
                                                     int* __restrict__ gcur1,
                                                     int* __restrict__ gcur2,
                                                     int* __restrict__ rowp1,
                                                     int* __restrict__ rowp2, int N, int E) {
  int tid = threadIdx.x;
  if (blockIdx.x < 64) {
    // LDS-aggregated 4096-bin histogram, private row per block (no zeroing)
    __shared__ int lh[4096];
    for (int i = tid; i < 4096; i += 256) lh[i] = 0;
    __syncthreads();
    int idx = blockIdx.x * 256 + tid;
    int stride = 64 * 256;
    for (int i = idx; i < n; i += stride) {
      unsigned key = f2key(score[i]);
      atomicAdd(&lh[key >> 20], 1);
    }
    __syncthreads();
    int* row = ghp + blockIdx.x * 4096;
    for (int i = tid; i < 4096; i += 256) row[i] = lh[i];
  } else {
    // bucket scan: 2-way-parallel row sums (64 rows) -> bases + cursors
    __shared__ int ss[128];
    __shared__ int pp[256];
    int bk = tid & 127, hf = tid >> 7;
    // CSR1
    {
      int vp = 0;
      if (bk < NBUCK)
        for (int r = hf * 32; r < hf * 32 + 32; ++r) vp += bh1p[r * 128 + bk];
      pp[tid] = vp;
    }
    __syncthreads();
    int v = 0;
    if (tid < 128) { v = pp[tid] + pp[tid + 128]; ss[tid] = v; }
    __syncthreads();
    for (int off = 1; off < 128; off <<= 1) {
      int a = 0, bsum = 0;
      if (tid < 128) { a = ss[tid]; bsum = (tid >= off) ? ss[tid - off] : 0; }
      __syncthreads();
      if (tid < 128) ss[tid] = a + bsum;
      __syncthreads();
    }
    if (tid < 128) {
      int excl = ss[tid] - v;
      if (tid < NBUCK) { bbase1[tid] = excl; gcur1[tid] = excl; }
      if (tid == NBUCK - 1) bbase1[NBUCK] = excl + v;
    }
    __syncthreads();
    // CSR2
    {
      int vp = 0;
      if (bk < NBUCK)
        for (int r = hf * 32; r < hf * 32 + 32; ++r) vp += bh2p[r * 128 + bk];
      pp[tid] = vp;
    }
    __syncthreads();
    int v2 = 0;
    if (tid < 128) { v2 = pp[tid] + pp[tid + 128]; ss[tid] = v2; }
    __syncthreads();
    for (int off = 1; off < 128; off <<= 1) {
      int a = 0, bsum = 0;
      if (tid < 128) { a = ss[tid]; bsum = (tid >= off) ? ss[tid - off] : 0; }
      __syncthreads();
      if (tid < 128) ss[tid] = a + bsum;
      __syncthreads();
    }
    if (tid < 128) {
      int excl = ss[tid] - v2;
      if (tid < NBUCK) { bbase2[tid] = excl; gcur2[tid] = excl; }
      if (tid == NBUCK - 1) bbase2[NBUCK] = excl + v2;
    }
    if (tid == 0) { rowp1[N] = E; rowp2[N] = E; }
  }
}

// ---------------- fused C (1024 thr): p1 conv [0,nb) | p1 dec [nb,2nb) |
// topk (block 2nb). p1: tile-ranked scatter, 8192 edges/block, 8/thread.
__global__ __launch_bounds__(1024) void fusedC_kernel(const int* __restrict__ ei,
                                                      const float* __restrict__ attr,
                                                      int* __restrict__ gcur1,
                                                      int2* __restrict__ stage1,
                                                      const int* __restrict__ ewi,
                                                      int* __restrict__ gcur2,
                                                      int2* __restrict__ stage2,
                                                      int E, int nb,
                                                      const float* __restrict__ score, int n, int k,
                                                      const int* __restrict__ ghp,
                                                      int* __restrict__ perm,
                                                      float* __restrict__ tts) {
  int tid = threadIdx.x;
  if ((int)blockIdx.x < 2 * nb) {
    bool conv = (int)blockIdx.x < nb;
    __shared__ int pcnt[128], pcur[128];
    int base = (conv ? blockIdx.x : blockIdx.x - nb) * 8192;
    int* gcur = conv ? gcur1 : gcur2;
    int2* stage = conv ? stage1 : stage2;
    if (tid < 128) pcnt[tid] = 0;
    __syncthreads();
    int bk[8];
    int2 pl[8];
#pragma unroll
    for (int i = 0; i < 8; ++i) {
      int e = base + i * 1024 + tid;
      bk[i] = -1;
      if (e < E) {
        if (conv) {
          int d = ei[E + e];
          int s = ei[e];
          bk[i] = d >> WSHIFT;
          pl[i] = make_int2(s | ((d & WMASK) << 16), __float_as_int(attr[e]));
        } else {
          int s = ewi[e];
          int d = ewi[E + e];
          bk[i] = s >> WSHIFT;
          pl[i] = make_int2(d | ((s & WMASK) << 16), e);
        }
        atomicAdd(&pcnt[bk[i]], 1);
      }
    }
    __syncthreads();
    if (tid < NBUCK) {
      int c = pcnt[tid];
      pcur[tid] = c ? atomicAdd(&gcur[tid], c) : 0;
    }
    __syncthreads();
#pragma unroll
    for (int i = 0; i < 8; ++i) {
      if (bk[i] >= 0) {
        int pos = atomicAdd(&pcur[bk[i]], 1);
        stage[pos] = pl[i];
      }
    }
  } else {
    // top-k: suffix-scan threshold (over 64 private rows) + collect + sort
    __shared__ int part[1024];
    __shared__ unsigned sT;
    int s0, s1, s2, s3;
    {
      int b0 = tid * 4;
      s0 = 0; s1 = 0; s2 = 0; s3 = 0;
      for (int r = 0; r < 64; ++r) {
        int4 v4 = *(const int4*)(ghp + r * 4096 + b0);
        s0 += v4.x; s1 += v4.y; s2 += v4.z; s3 += v4.w;
      }
      part[tid] = s0 + s1 + s2 + s3;
      __syncthreads();
      for (int off = 1; off < 1024; off <<= 1) {
        int v = part[tid];
        int add = (tid + off < 1024) ? part[tid + off] : 0;
        __syncthreads();
        part[tid] = v + add;
        __syncthreads();
      }
      int sufChunk = part[tid];
      int sufNext = (tid < 1023) ? part[tid + 1] : 0;
      if (sufNext < k && sufChunk >= k) {
        int run = sufNext;
        int b;
        run += s3;
        if (run >= k) b = tid * 4 + 3;
        else {
          run += s2;
          if (run >= k) b = tid * 4 + 2;
          else {
            run += s1;
            b = (run >= k) ? tid * 4 + 1 : tid * 4;
          }
        }
        sT = ((unsigned)b) << 20;
      }
    }
    __syncthreads();
    unsigned T = sT;
    __shared__ unsigned keys[1024];
    __shared__ int idxs[1024];
    __shared__ int cnt;
    if (tid == 0) cnt = 0;
    keys[tid] = 0u;
    idxs[tid] = 0x7fffffff;
    __syncthreads();
    for (int i = tid; i < n; i += 1024) {
      unsigned key = f2key(score[i]);
      if (key >= T) {
        int p = atomicAdd(&cnt, 1);
        if (p < 1024) { keys[p] = key; idxs[p] = i; }
      }
    }
    __syncthreads();
    for (int size = 2; size <= 1024; size <<= 1) {
      for (int stride = size >> 1; stride > 0; stride >>= 1) {
        int j = tid ^ stride;
        if (j > tid) {
          unsigned ka = keys[tid], kb = keys[j];
          int ia = idxs[tid], ib = idxs[j];
          bool aBefore = (ka > kb) || (ka == kb && ia < ib);
          bool up = ((tid & size) == 0);
          if (aBefore != up) {
            keys[tid] = kb; keys[j] = ka;
            idxs[tid] = ib; idxs[j] = ia;
          }
        }
        __syncthreads();
      }
    }
    if (tid < k) {
      int idx = idxs[tid];
      perm[tid] = idx;
      tts[tid] = tanhf(score[idx]);
    }
  }
}

// ---------------- fused D (256 thr): gru (blocks 0..255) || p2 (256..451) --
// gru: COALESCED packed-bf16 transposed weights (WT2[p*768+r], lane-consec);
// writes evolved W TRANSPOSED bf16: WevoT[n*256+k] = W[k][n].
__global__ __launch_bounds__(256) void fusedD_kernel(const float* __restrict__ x,
                                                     const int* __restrict__ perm,
                                                     const float* __restrict__ tts,
                                                     const float* __restrict__ Wi,
                                                     const unsigned* __restrict__ WihT2,
                                                     const unsigned* __restrict__ WhhT2,
                                                     const float* __restrict__ b_ih,
                                                     const float* __restrict__ b_hh,
                                                     unsigned short* __restrict__ WevoT,
                                                     const int2* __restrict__ stage1,
                                                     const int* __restrict__ bbase1,
                                                     int2* __restrict__ esv,
                                                     int* __restrict__ rowp1,
                                                     float* __restrict__ dinv,
                                                     const int2* __restrict__ stage2,
                                                     const int* __restrict__ bbase2,
                                                     int2* __restrict__ eto,
                                                     int* __restrict__ rowp2, int N) {
  int tid = threadIdx.x;
  if (blockIdx.x < 256) {
    // GRU step with x_tilde inline; coalesced packed weight reads
    int i = blockIdx.x, j = tid;
    __shared__ float sx[256], sh[256];
    sx[j] = x[(size_t)perm[i] * 256 + j] * tts[i];
    sh[j] = Wi[i * 256 + j];
    __syncthreads();
    float gi[3], gh[3];
#pragma unroll
    for (int g = 0; g < 3; ++g) {
      int r = g * 256 + j;
      const unsigned* wi = WihT2 + r;
      const unsigned* wh = WhhT2 + r;
      float si = 0.f, s2 = 0.f;
      const float2* sx2 = (const float2*)sx;
      const float2* sh2 = (const float2*)sh;
#pragma unroll 4
      for (int pp = 0; pp < 128; ++pp) {
        unsigned a = wi[pp * 768];
        unsigned hb = wh[pp * 768];
        float2 xv = sx2[pp];
        float2 hv = sh2[pp];
        si += xv.x * bf2f((unsigned short)(a & 0xffff)) +
              xv.y * bf2f((unsigned short)(a >> 16));
        s2 += hv.x * bf2f((unsigned short)(hb & 0xffff)) +
              hv.y * bf2f((unsigned short)(hb >> 16));
      }
      gi[g] = si + b_ih[r];
      gh[g] = s2 + b_hh[r];
    }
    float r = 1.f / (1.f + expf(-(gi[0] + gh[0])));
    float z = 1.f / (1.f + expf(-(gi[1] + gh[1])));
    float nn = tanhf(gi[2] + r * gh[2]);
    float w = (1.f - z) * nn + z * sh[j];
    WevoT[(size_t)j * 256 + i] = f2bf(w);
  } else {
    // p2: per-bucket node histogram + scan + node-ordered CSR write
    __shared__ int cnt[512];
    __shared__ float degs[512];
    __shared__ int pref[512];
    __shared__ int ss[256];
    int bb2 = blockIdx.x - 256;
    bool isConv = bb2 < NBUCK;
    int b = isConv ? bb2 : bb2 - NBUCK;
    const int2* stage = isConv ? stage1 : stage2;
    const int* bbase = isConv ? bbase1 : bbase2;
    int beg = bbase[b], end = bbase[b + 1];
    int node0 = b << WSHIFT;
    cnt[tid] = 0; cnt[tid + 256] = 0;
    degs[tid] = 0.f; degs[tid + 256] = 0.f;
    __syncthreads();
    for (int j = beg + tid; j < end; j += 256) {
      int2 p = stage[j];
      int loc = p.x >> 16;
      atomicAdd(&cnt[loc], 1);
      if (isConv) atomicAdd(&degs[loc], __int_as_float(p.y));
    }
    __syncthreads();
    int c0 = cnt[2 * tid], c1 = cnt[2 * tid + 1];
    ss[tid] = c0 + c1;
    __syncthreads();
    for (int off = 1; off < 256; off <<= 1) {
      int a = ss[tid];
      int bsum = (tid >= off) ? ss[tid - off] : 0;
      __syncthreads();
      ss[tid] = a + bsum;
      __syncthreads();
    }
    int excl = (tid ? ss[tid - 1] : 0);
    pref[2 * tid] = excl;
    pref[2 * tid + 1] = excl + c0;
    __syncthreads();
#pragma unroll
    for (int h = 0; h < 2; ++h) {
      int i = tid + h * 256;
      int node = node0 + i;
      if (node < N) {
        if (isConv) {
          rowp1[node] = beg + pref[i];
          float d = degs[i];
          dinv[node] = d > 0.f ? 1.f / sqrtf(d) : 0.f;
        } else {
          rowp2[node] = beg + pref[i];
        }
      }
    }
    __syncthreads();
    int2* outb = isConv ? esv : eto;
    for (int j = beg + tid; j < end; j += 256) {
      int2 p = stage[j];
      int loc = p.x >> 16;
      int pos = beg + atomicAdd(&pref[loc], 1);
      outb[pos] = make_int2(p.x & 0xFFFF, p.y);
    }
  }
}

// ---------------------------------------------------------------------------
// m97-structure bf16 MFMA GEMM: per blockIdx.y,
//   C[M,256] = A[M,256] @ (BT[by*256 .. by*256+255][256])^T   (bf16 in/out)
// 128x256 tile, 8 waves, BK=32, global_load_lds staging, 2-barrier K-loop.
// ---------------------------------------------------------------------------
__global__ __launch_bounds__(512) void mfma_gemm128(const unsigned short* __restrict__ A,
                                                    const unsigned short* __restrict__ BT,
                                                    unsigned short* __restrict__ C1,
                                                    unsigned short* __restrict__ C2,
                                                    int M) {
  __shared__ unsigned short sA[128 * 32];
  __shared__ unsigned short sB[256 * 32];
  int tid = threadIdx.x;
  int wave = tid >> 6, lane = tid & 63;
  int quad = lane >> 4, r16 = lane & 15;
  int wm = wave >> 2, wn = wave & 3;
  int mbase = blockIdx.x * 128;
  const unsigned short* Bt = BT + ((size_t)blockIdx.y << 16);
  unsigned short* Cout = blockIdx.y ? C2 : C1;

  int srow = tid >> 2, scolq = tid & 3;
  const unsigned short* gA = A + (size_t)(mbase + srow) * 256 + scolq * 8;
  const unsigned short* gB0 = Bt + (size_t)srow * 256 + scolq * 8;
  const unsigned short* gB1 = Bt + (size_t)(128 + srow) * 256 + scolq * 8;
  unsigned short* lA = sA + wave * 512;
  unsigned short* lB0 = sB + wave * 512;
  unsigned short* lB1 = sB + 4096 + wave * 512;

  f32x4 acc[4][4];
#pragma unroll
  for (int i = 0; i < 4; ++i)
#pragma unroll
    for (int j = 0; j < 4; ++j) acc[i][j] = (f32x4){0.f, 0.f, 0.f, 0.f};

  const unsigned short* pA = sA + (wm * 64 + r16) * 32 + quad * 8;
  const unsigned short* pB = sB + (wn * 64 + r16) * 32 + quad * 8;

  for (int k0 = 0; k0 < 256; k0 += 32) {
    if (k0) __syncthreads();
    gload16(gA + k0, lA);
    gload16(gB0 + k0, lB0);
    gload16(gB1 + k0, lB1);
    __syncthreads();
    bf16x8 af[4], bfr[4];
#pragma unroll
    for (int mt = 0; mt < 4; ++mt) af[mt] = *(const bf16x8*)(pA + mt * 512);
#pragma unroll
    for (int nt = 0; nt < 4; ++nt) bfr[nt] = *(const bf16x8*)(pB + nt * 512);
#pragma unroll
    for (int mt = 0; mt < 4; ++mt)
#pragma unroll
      for (int nt = 0; nt < 4; ++nt)
        acc[mt][nt] = __builtin_amdgcn_mfma_f32_16x16x32_bf16(af[mt], bfr[nt], acc[mt][nt], 0, 0, 0);
  }
#pragma unroll
  for (int mt = 0; mt < 4; ++mt) {
#pragma unroll
    for (int rr = 0; rr < 4; ++rr) {
      int grow = mbase + wm * 64 + mt * 16 + quad * 4 + rr;
      if (grow < M) {
#pragma unroll
        for (int nt = 0; nt < 4; ++nt)
          Cout[(size_t)grow * 256 + wn * 64 + nt * 16 + r16] = f2bf(acc[mt][nt][rr]);
      }
    }
  }
}

// one wave per dst node, quad decomposition: 16 lanes/edge x 4 edges/group.
// Per 64-edge chunk: lane l coalesced-loads meta esv[cb+l] and applies
// dinv[src] once (L2-resident), then stage refills broadcast src/v via shfl
// (refill chain rows-only). 3-stage in-place prefetch.
__global__ __launch_bounds__(256) void gcn_gather(const unsigned short* __restrict__ xw,
                                                  const int* __restrict__ row_ptr,
                                                  const int2* __restrict__ esv,
                                                  const float* __restrict__ dinv,
                                                  unsigned short* __restrict__ ne, int N) {
  int node = blockIdx.x * 4 + (threadIdx.x >> 6);
  int lane = threadIdx.x & 63;
  int g = lane & 15, q = lane >> 4;
  if (node >= N) return;
  int beg = row_ptr[node], end = row_ptr[node + 1];
  float acc[16];
#pragma unroll
  for (int c = 0; c < 16; ++c) acc[c] = 0.f;
  const unsigned short* xb = xw + g * 16;

  for (int cb = beg; cb < end; cb += 64) {
    int cend = cb + 64 < end ? cb + 64 : end;
    int me = cb + lane;
    int2 mm = (me < cend) ? esv[me] : make_int2(0, 0);
    int mx = mm.x;
    float mv = __int_as_float(mm.y) * dinv[mx];

    float vA = 0.f, vB = 0.f, vC = 0.f;
    u16x8 rAa, rAb, rBa, rBb, rCa, rCb;
    {
      int e = cb + q;
      int sx = __shfl(mx, q, 64);
      float tv = __shfl(mv, q, 64);
      vA = (e < cend) ? tv : 0.f;
      rAa = *(const u16x8*)(xb + (size_t)sx * 256);
      rAb = *(const u16x8*)(xb + (size_t)sx * 256 + 8);
    }
    if (cb + 4 < cend) {
      int e = cb + 4 + q;
      int sx = __shfl(mx, 4 + q, 64);
      float tv = __shfl(mv, 4 + q, 64);
      vB = (e < cend) ? tv : 0.f;
      rBa = *(const u16x8*)(xb + (size_t)sx * 256);
      rBb = *(const u16x8*)(xb + (size_t)sx * 256 + 8);
    } else { rBa = rAa; rBb = rAb; }
    if (cb + 8 < cend) {
      int e = cb + 8 + q;
      int sx = __shfl(mx, 8 + q, 64);
      float tv = __shfl(mv, 8 + q, 64);
      vC = (e < cend) ? tv : 0.f;
      rCa = *(const u16x8*)(xb + (size_t)sx * 256);
      rCb = *(const u16x8*)(xb + (size_t)sx * 256 + 8);
    } else { rCa = rAa; rCb = rAb; }

    for (int jb = cb; jb < cend; jb += 12) {
      // consume A, refill A <- jb+12
#pragma unroll
      for (int c = 0; c < 8; ++c) acc[c] += bf2f(rAa[c]) * vA;
#pragma unroll
      for (int c = 0; c < 8; ++c) acc[8 + c] += bf2f(rAb[c]) * vA;
      vA = 0.f;
      if (jb + 12 < cend) {
        int e = jb + 12 + q;
        int idx = (e - cb) & 63;
        int sx = __shfl(mx, idx, 64);
        float tv = __shfl(mv, idx, 64);
        vA = (e < cend) ? tv : 0.f;
        rAa = *(const u16x8*)(xb + (size_t)sx * 256);
        rAb = *(const u16x8*)(xb + (size_t)sx * 256 + 8);
      }
      // consume B, refill B <- jb+16
#pragma unroll
      for (int c = 0; c < 8; ++c) acc[c] += bf2f(rBa[c]) * vB;
#pragma unroll
      for (int c = 0; c < 8; ++c) acc[8 + c] += bf2f(rBb[c]) * vB;
      vB = 0.f;
      if (jb + 16 < cend) {
        int e = jb + 16 + q;
        int idx = (e - cb) & 63;
        int sx = __shfl(mx, idx, 64);
        float tv = __shfl(mv, idx, 64);
        vB = (e < cend) ? tv : 0.f;
        rBa = *(const u16x8*)(xb + (size_t)sx * 256);
        rBb = *(const u16x8*)(xb + (size_t)sx * 256 + 8);
      }
      // consume C, refill C <- jb+20
#pragma unroll
      for (int c = 0; c < 8; ++c) acc[c] += bf2f(rCa[c]) * vC;
#pragma unroll
      for (int c = 0; c < 8; ++c) acc[8 + c] += bf2f(rCb[c]) * vC;
      vC = 0.f;
      if (jb + 20 < cend) {
        int e = jb + 20 + q;
        int idx = (e - cb) & 63;
        int sx = __shfl(mx, idx, 64);
        float tv = __shfl(mv, idx, 64);
        vC = (e < cend) ? tv : 0.f;
        rCa = *(const u16x8*)(xb + (size_t)sx * 256);
        rCb = *(const u16x8*)(xb + (size_t)sx * 256 + 8);
      }
    }
  }
  // cross-quad combine (each quad holds a partial over the same channels)
#pragma unroll
  for (int c = 0; c < 16; ++c) {
    acc[c] += __shfl_xor(acc[c], 16, 64);
    acc[c] += __shfl_xor(acc[c], 32, 64);
  }
  if (q == 0) {
    float dd = dinv[node];
    u16x8 o0, o1;
#pragma unroll
    for (int c = 0; c < 8; ++c) {
      o0[c] = f2bf(acc[c] * dd);
      o1[c] = f2bf(acc[8 + c] * dd);
    }
    *(u16x8*)(ne + (size_t)node * 256 + g * 16) = o0;
    *(u16x8*)(ne + (size_t)node * 256 + g * 16 + 8) = o1;
  }
}

// decode grouped by src, one wave per node, quad decomposition. Per-chunk
// meta preload + shfl broadcast; 3-stage in-place prefetch; DPP row_ror
// reduce. A[s]+b1 and w2 register-resident per lane (16 channels).
__global__ __launch_bounds__(256) void edge_decode_csr(const unsigned short* __restrict__ A,
                                                       const unsigned short* __restrict__ Bm,
                                                       const int* __restrict__ row_ptr,
                                                       const int2* __restrict__ eto,
                                                       const float* __restrict__ b1,
                                                       const float* __restrict__ w2,
                                                       const float* __restrict__ b2,
                                                       float* __restrict__ out, int N) {
  int node = blockIdx.x * 4 + (threadIdx.x >> 6);
  int lane = threadIdx.x & 63;
  int g = lane & 15, q = lane >> 4;
  if (node >= N) return;
  int beg = row_ptr[node], end = row_ptr[node + 1];
  if (beg >= end) return;
  float a[16], w[16];
  {
    u16x8 a0 = *(const u16x8*)(A + (size_t)node * 256 + g * 16);
    u16x8 a1 = *(const u16x8*)(A + (size_t)node * 256 + g * 16 + 8);
    const float4* bp = (const float4*)(b1 + g * 16);
    const float4* wp = (const float4*)(w2 + g * 16);
#pragma unroll
    for (int i = 0; i < 4; ++i) {
      float4 bv = bp[i];
      float4 wv = wp[i];
      a[i * 4 + 0] = (i < 2 ? bf2f(a0[i * 4 + 0]) : bf2f(a1[i * 4 - 8])) + bv.x;
      a[i * 4 + 1] = (i < 2 ? bf2f(a0[i * 4 + 1]) : bf2f(a1[i * 4 - 7])) + bv.y;
      a[i * 4 + 2] = (i < 2 ? bf2f(a0[i * 4 + 2]) : bf2f(a1[i * 4 - 6])) + bv.z;
      a[i * 4 + 3] = (i < 2 ? bf2f(a0[i * 4 + 3]) : bf2f(a1[i * 4 - 5])) + bv.w;
      w[i * 4 + 0] = wv.x;
      w[i * 4 + 1] = wv.y;
      w[i * 4 + 2] = wv.z;
      w[i * 4 + 3] = wv.w;
    }
  }
  float base = b2[0];
  const unsigned short* Bb = Bm + g * 16;

  for (int cb = beg; cb < end; cb += 64) {
    int cend = cb + 64 < end ? cb + 64 : end;
    int me = cb + lane;
    int2 mm = (me < cend) ? eto[me] : make_int2(0, 0);
    int mx = mm.x, my = mm.y;

    bool okA = false, okB = false, okC = false;
    int oA = 0, oB = 0, oC = 0;
    u16x8 rAa, rAb, rBa, rBb, rCa, rCb;
    {
      int e = cb + q;
      int sx = __shfl(mx, q, 64);
      oA = __shfl(my, q, 64);
      okA = e < cend;
      rAa = *(const u16x8*)(Bb + (size_t)sx * 256);
      rAb = *(const u16x8*)(Bb + (size_t)sx * 256 + 8);
    }
    if (cb + 4 < cend) {
      int e = cb + 4 + q;
      int sx = __shfl(mx, 4 + q, 64);
      oB = __shfl(my, 4 + q, 64);
      okB = e < cend;
      rBa = *(const u16x8*)(Bb + (size_t)sx * 256);
      rBb = *(const u16x8*)(Bb + (size_t)sx * 256 + 8);
    } else { rBa = rAa; rBb = rAb; }
    if (cb + 8 < cend) {
      int e = cb + 8 + q;
      int sx = __shfl(mx, 8 + q, 64);
      oC = __shfl(my, 8 + q, 64);
      okC = e < cend;
      rCa = *(const u16x8*)(Bb + (size_t)sx * 256);
      rCb = *(const u16x8*)(Bb + (size_t)sx * 256 + 8);
    } else { rCa = rAa; rCb = rAb; }

    for (int jb = cb; jb < cend; jb += 12) {
      // consume A
      {
        float s0 = 0.f, s1 = 0.f;
#pragma unroll
        for (int c = 0; c < 8; ++c) s0 += fmaxf(a[c] + bf2f(rAa[c]), 0.f) * w[c];
#pragma unroll
        for (int c = 0; c < 8; ++c) s1 += fmaxf(a[8 + c] + bf2f(rAb[c]), 0.f) * w[8 + c];
        float s = s0 + s1;
        s = dpp_add<0x128>(s);  // row_ror:8
        s = dpp_add<0x124>(s);  // row_ror:4
        s = dpp_add<0x122>(s);  // row_ror:2
        s = dpp_add<0x121>(s);  // row_ror:1
        if (g == 0 && okA) out[oA] = s + base;
      }
      // refill A <- jb+12
      okA = false;
      if (jb + 12 < cend) {
        int e = jb + 12 + q;
        int idx = (e - cb) & 63;
        int sx = __shfl(mx, idx, 64);
        oA = __shfl(my, idx, 64);
        okA = e < cend;
        rAa = *(const u16x8*)(Bb + (size_t)sx * 256);
        rAb = *(const u16x8*)(Bb + (size_t)sx * 256 + 8);
      }
      // consume B
      {
        float s0 = 0.f, s1 = 0.f;
#pragma unroll
        for (int c = 0; c < 8; ++c) s0 += fmaxf(a[c] + bf2f(rBa[c]), 0.f) * w[c];
#pragma unroll
        for (int c = 0; c < 8; ++c) s1 += fmaxf(a[8 + c] + bf2f(rBb[c]), 0.f) * w[8 + c];
        float s = s0 + s1;
        s = dpp_add<0x128>(s);
        s = dpp_add<0x124>(s);
        s = dpp_add<0x122>(s);
        s = dpp_add<0x121>(s);
        if (g == 0 && okB) out[oB] = s + base;
      }
      // refill B <- jb+16
      okB = false;
      if (jb + 16 < cend) {
        int e = jb + 16 + q;
        int idx = (e - cb) & 63;
        int sx = __shfl(mx, idx, 64);
        oB = __shfl(my, idx, 64);
        okB = e < cend;
        rBa = *(const u16x8*)(Bb + (size_t)sx * 256);
        rBb = *(const u16x8*)(Bb + (size_t)sx * 256 + 8);
      }
      // consume C
      {
        float s0 = 0.f, s1 = 0.f;
#pragma unroll
        for (int c = 0; c < 8; ++c) s0 += fmaxf(a[c] + bf2f(rCa[c]), 0.f) * w[c];
#pragma unroll
        for (int c = 0; c < 8; ++c) s1 += fmaxf(a[8 + c] + bf2f(rCb[c]), 0.f) * w[8 + c];
        float s = s0 + s1;
        s = dpp_add<0x128>(s);
        s = dpp_add<0x124>(s);
        s = dpp_add<0x122>(s);
        s = dpp_add<0x121>(s);
        if (g == 0 && okC) out[oC] = s + base;
      }
      // refill C <- jb+20
      okC = false;
      if (jb + 20 < cend) {
        int e = jb + 20 + q;
        int idx = (e - cb) & 63;
        int sx = __shfl(mx, idx, 64);
        oC = __shfl(my, idx, 64);
        okC = e < cend;
        rCa = *(const u16x8*)(Bb + (size_t)sx * 256);
        rCb = *(const u16x8*)(Bb + (size_t)sx * 256 + 8);
      }
    }
  }
}

extern "C" void kernel_launch(void* const* d_in, const int* in_sizes, int n_in,
                              void* d_out, int out_size, void* d_ws, size_t ws_size,
                              hipStream_t stream) {
  const float* x      = (const float*)d_in[0];
  const int*   ei     = (const int*)d_in[1];
  const float* attr   = (const float*)d_in[2];
  const int*   ewi    = (const int*)d_in[3];
  const float* p_pool = (const float*)d_in[4];
  const float* W_ih   = (const float*)d_in[5];
  const float* W_hh   = (const float*)d_in[6];
  const float* b_ih   = (const float*)d_in[7];
  const float* b_hh   = (const float*)d_in[8];
  const float* W_init = (const float*)d_in[9];
  const float* lin1_w = (const float*)d_in[10];
  const float* lin1_b = (const float*)d_in[11];
  const float* lin2_w = (const float*)d_in[12];
  const float* lin2_b = (const float*)d_in[13];
  float* out = (float*)d_out;

  const int C = 256;
  const int N = in_sizes[0] / C;   // 50000
  const int E = in_sizes[2];       // 800000

  // ---- workspace layout (256B aligned) ----
  char* ws = (char*)d_ws;
  size_t off = 0;
  auto alloc = [&](size_t bytes) {
    size_t o = off;
    off = (off + bytes + 255) & ~(size_t)255;
    return o;
  };
  float*          score  = (float*)(ws + alloc((size_t)N * 4));
  int*            perm   = (int*)(ws + alloc(C * 4));
  float*          tts    = (float*)(ws + alloc(C * 4));
  unsigned short* WevoT  = (unsigned short*)(ws + alloc((size_t)C * C * 2));
  unsigned short* WAB    = (unsigned short*)(ws + alloc((size_t)2 * C * C * 2));
  unsigned*       WihT2  = (unsigned*)(ws + alloc((size_t)128 * 768 * 4));
  unsigned*       WhhT2  = (unsigned*)(ws + alloc((size_t)128 * 768 * 4));
  int*            bh1p   = (int*)(ws + alloc((size_t)64 * 128 * 4));
  int*            bh2p   = (int*)(ws + alloc((size_t)64 * 128 * 4));
  int*            ghp    = (int*)(ws + alloc((size_t)64 * 4096 * 4));
  int*            bbase1 = (int*)(ws + alloc((NBUCK + 1) * 4));
  int*            bbase2 = (int*)(ws + alloc((NBUCK + 1) * 4));
  int*            gcur1  = (int*)(ws + alloc(128 * 4));
  int*            gcur2  = (int*)(ws + alloc(128 * 4));
  float*          dinv   = (float*)(ws + alloc((size_t)N * 4));
  int*            rowp1  = (int*)(ws + alloc((size_t)(N + 1) * 4));
  int*            rowp2  = (int*)(ws + alloc((size_t)(N + 1) * 4));
  int2*           stage1 = (int2*)(ws + alloc((size_t)E * 8));
  int2*           stage2 = (int2*)(ws + alloc((size_t)E * 8));
  int2*           esv    = (int2*)(ws + alloc((size_t)E * 8));
  int2*           eto    = (int2*)(ws + alloc((size_t)E * 8));
  unsigned short* xh     = (unsigned short*)(ws + alloc((size_t)N * C * 2));
  unsigned short* xwh    = (unsigned short*)(ws + alloc((size_t)N * C * 2));
  unsigned short* Bbf    = (unsigned short*)(ws + alloc((size_t)N * C * 2));
  // aliases (stream-ordered producers/consumers):
  unsigned short* ne  = xh;   // xh dead after GEMM1
  unsigned short* Abf = xwh;  // xwh dead after gather

  int NS = (N + 3) / 4;            // 12500 score blocks
  int nbP1 = (E + 8191) / 8192;    // 98 (1024-thread p1 blocks)

  // A) bhist [0,64) || score_cast || lin1cast (512) || wT pack (768)
  fusedA_kernel<<<64 + NS + 512 + 768, 256, 0, stream>>>(x, p_pool, score, xh, N, NS,
                                                         ei, ewi, bh1p, bh2p, E,
                                                         lin1_w, WAB,
                                                         W_ih, W_hh, WihT2, WhhT2);

  // B) hist12 private rows (64 blocks) || bucket_scan (block 64, 2-way sums)
  fusedB_kernel<<<65, 256, 0, stream>>>(score, N, ghp, bh1p, bh2p,
                                        bbase1, bbase2, gcur1, gcur2,
                                        rowp1, rowp2, N, E);

  // C) p1 conv+dec (2*98 blocks, 8192 edges each) || topk (block 196)
  fusedC_kernel<<<2 * nbP1 + 1, 1024, 0, stream>>>(ei, attr, gcur1, stage1,
                                                   ewi, gcur2, stage2, E, nbP1,
                                                   score, N, C, ghp, perm, tts);

  // D) gru (256 blocks, coalesced packed weights) || p2 (196 blocks)
  fusedD_kernel<<<256 + 2 * NBUCK, 256, 0, stream>>>(x, perm, tts, W_init,
                                                     WihT2, WhhT2, b_ih, b_hh, WevoT,
                                                     stage1, bbase1, esv, rowp1, dinv,
                                                     stage2, bbase2, eto, rowp2, N);

  // E) xw = x @ Wevo (also acts as L2 prefetch for gather's random reads)
  mfma_gemm128<<<dim3((N + 127) / 128, 1), 512, 0, stream>>>(xh, WevoT, xwh, xwh, N);

  // F) gather (per-node waves; dinv applied at meta preload; xwh L2-warm)
  gcn_gather<<<NS, 256, 0, stream>>>(xwh, rowp1, esv, dinv, ne, N);

  // G) decoder projections: stacked BT (WA^T | WB^T), gridDim.y = 2
  mfma_gemm128<<<dim3((N + 127) / 128, 2), 512, 0, stream>>>(ne, WAB, Abf, Bbf, N);

  // H) edge decode (per-node waves, 3-stage prefetch + DPP reduce)
  edge_decode_csr<<<NS, 256, 0, stream>>>(Abf, Bbf, rowp2, eto,
                                          lin1_b, lin2_w, lin2_b, out, N);
}